// Round 3
// baseline (1249.035 us; speedup 1.0000x reference)
//
#include <hip/hip_runtime.h>

#define NN 100000      // nodes
#define NE 1200000     // edges
#define FIN 22
#define HD 64
#define NC 6
#define BN_EPS 1e-5f
#define SCAN_B 256
#define SCAN_NB ((NN + SCAN_B - 1) / SCAN_B)   // 391

struct Entry { int s; float c; };   // src node, edge coefficient

// ---------------- CSR build ----------------
__global__ void k_zero_cnt(int* __restrict__ cnt) {
    int i = blockIdx.x * blockDim.x + threadIdx.x;
    if (i < NN) cnt[i] = 0;
}

__global__ void k_hist(const int* __restrict__ dst, int* __restrict__ cnt) {
    int e = blockIdx.x * blockDim.x + threadIdx.x;
    if (e < NE) atomicAdd(&cnt[dst[e]], 1);
}

__global__ void k_dinv(const int* __restrict__ cnt, float* __restrict__ dinv) {
    int i = blockIdx.x * blockDim.x + threadIdx.x;
    if (i < NN) dinv[i] = rsqrtf((float)cnt[i] + 1.0f);  // +1 self loop
}

// exclusive scan, level 1
__global__ void k_scan1(const int* __restrict__ cnt, int* __restrict__ row_ptr,
                        int* __restrict__ partials) {
    __shared__ int s[SCAN_B];
    int t = threadIdx.x;
    int i = blockIdx.x * SCAN_B + t;
    int v = (i < NN) ? cnt[i] : 0;
    s[t] = v;
    __syncthreads();
    for (int off = 1; off < SCAN_B; off <<= 1) {
        int x = (t >= off) ? s[t - off] : 0;
        __syncthreads();
        s[t] += x;
        __syncthreads();
    }
    if (i < NN) row_ptr[i] = s[t] - v;
    if (t == SCAN_B - 1) partials[blockIdx.x] = s[t];
}

__global__ void k_scan2(int* __restrict__ partials) {
    __shared__ int s[512];
    int t = threadIdx.x;
    int v = (t < SCAN_NB) ? partials[t] : 0;
    s[t] = v;
    __syncthreads();
    for (int off = 1; off < 512; off <<= 1) {
        int x = (t >= off) ? s[t - off] : 0;
        __syncthreads();
        s[t] += x;
        __syncthreads();
    }
    if (t < SCAN_NB) partials[t] = s[t] - v;
}

__global__ void k_scan3(int* __restrict__ row_ptr, int* __restrict__ cursor,
                        const int* __restrict__ partials) {
    int i = blockIdx.x * SCAN_B + threadIdx.x;
    if (i < NN) {
        int v = row_ptr[i] + partials[blockIdx.x];
        row_ptr[i] = v;
        cursor[i] = v;
    }
    if (i == 0) row_ptr[NN] = NE;
}

__global__ void k_fill(const int* __restrict__ src, const int* __restrict__ dst,
                       const float* __restrict__ dinv, int* __restrict__ cursor,
                       Entry* __restrict__ entries) {
    int e = blockIdx.x * blockDim.x + threadIdx.x;
    if (e >= NE) return;
    int s = src[e], d = dst[e];
    int p = atomicAdd(&cursor[d], 1);
    Entry en;
    en.s = s;
    en.c = dinv[s] * dinv[d];
    entries[p] = en;
}

// ---------------- embed: h = relu(x @ W_emb + b_emb) ----------------
__global__ void k_embed(const float* __restrict__ x, const float* __restrict__ W,
                        const float* __restrict__ b, float* __restrict__ h) {
    __shared__ float Ws[FIN * HD];
    __shared__ float xs[4][FIN];
    int t = threadIdx.x;
    for (int i = t; i < FIN * HD; i += 256) Ws[i] = W[i];
    int n0 = blockIdx.x * 4;
    for (int i = t; i < 4 * FIN; i += 256) {
        int n = n0 + i / FIN;
        xs[i / FIN][i % FIN] = (n < NN) ? x[(long)n * FIN + i % FIN] : 0.f;
    }
    __syncthreads();
    int local = t >> 6;
    int f = t & 63;
    int n = n0 + local;
    if (n < NN) {
        float acc = b[f];
#pragma unroll
        for (int k = 0; k < FIN; ++k) acc = fmaf(xs[local][k], Ws[k * HD + f], acc);
        h[(long)n * HD + f] = fmaxf(acc, 0.f);
    }
}

// ---------------- layer GEMM: hw = hin @ W ----------------
// 64 nodes/block; h staged TRANSPOSED in LDS; thread = 4 nodes x 4 features,
// all inner-loop LDS reads are ds_read_b128.
__global__ void k_gemm(const float* __restrict__ hin, const float* __restrict__ W,
                       float* __restrict__ hw) {
    __shared__ float Ws[HD * HD];       // 16 KB, row-major [k][f]
    __shared__ float hsT[HD * 64];      // 16 KB, [k][node]
    int t = threadIdx.x;
    // stage W (1024 float4)
    for (int i = t; i < 1024; i += 256)
        reinterpret_cast<float4*>(Ws)[i] = reinterpret_cast<const float4*>(W)[i];
    int n0 = blockIdx.x * 64;
    // stage 64 h rows transposed (read float4 rows, scatter to [k][node])
    for (int i = t; i < 1024; i += 256) {
        int node = i & 63;
        int kq = i >> 6;                // 0..15
        int n = n0 + node;
        float4 val = (n < NN) ? *reinterpret_cast<const float4*>(&hin[(long)n * HD + kq * 4])
                              : make_float4(0.f, 0.f, 0.f, 0.f);
        hsT[(kq * 4 + 0) * 64 + node] = val.x;
        hsT[(kq * 4 + 1) * 64 + node] = val.y;
        hsT[(kq * 4 + 2) * 64 + node] = val.z;
        hsT[(kq * 4 + 3) * 64 + node] = val.w;
    }
    __syncthreads();
    int fq = t & 15;                    // feature quad
    int ng = t >> 4;                    // node group (0..15), nodes ng*4..+3
    float4 a0 = {0,0,0,0}, a1 = {0,0,0,0}, a2 = {0,0,0,0}, a3 = {0,0,0,0};
#pragma unroll
    for (int k = 0; k < HD; ++k) {
        float4 w = *reinterpret_cast<const float4*>(&Ws[k * HD + fq * 4]);
        float4 h4 = *reinterpret_cast<const float4*>(&hsT[k * 64 + ng * 4]);
        a0.x = fmaf(h4.x, w.x, a0.x); a0.y = fmaf(h4.x, w.y, a0.y);
        a0.z = fmaf(h4.x, w.z, a0.z); a0.w = fmaf(h4.x, w.w, a0.w);
        a1.x = fmaf(h4.y, w.x, a1.x); a1.y = fmaf(h4.y, w.y, a1.y);
        a1.z = fmaf(h4.y, w.z, a1.z); a1.w = fmaf(h4.y, w.w, a1.w);
        a2.x = fmaf(h4.z, w.x, a2.x); a2.y = fmaf(h4.z, w.y, a2.y);
        a2.z = fmaf(h4.z, w.z, a2.z); a2.w = fmaf(h4.z, w.w, a2.w);
        a3.x = fmaf(h4.w, w.x, a3.x); a3.y = fmaf(h4.w, w.y, a3.y);
        a3.z = fmaf(h4.w, w.z, a3.z); a3.w = fmaf(h4.w, w.w, a3.w);
    }
    int nb = n0 + ng * 4;
    if (nb + 0 < NN) *reinterpret_cast<float4*>(&hw[(long)(nb + 0) * HD + fq * 4]) = a0;
    if (nb + 1 < NN) *reinterpret_cast<float4*>(&hw[(long)(nb + 1) * HD + fq * 4]) = a1;
    if (nb + 2 < NN) *reinterpret_cast<float4*>(&hw[(long)(nb + 2) * HD + fq * 4]) = a2;
    if (nb + 3 < NN) *reinterpret_cast<float4*>(&hw[(long)(nb + 3) * HD + fq * 4]) = a3;
}

// ---------------- fused gather + self-loop + bias + BN + ReLU ----------------
// one 64-lane wave per node; 4 groups x 16 lanes; group g handles edges b0+g, b0+g+4, ...
// each lane holds float4 of features; 4 row-gathers in flight + entry prefetch.
__global__ void k_gather_bn(const float* __restrict__ hw, const float* __restrict__ dinv,
                            const int* __restrict__ row_ptr, const Entry* __restrict__ entries,
                            const float* __restrict__ bias, const float* __restrict__ g,
                            const float* __restrict__ be, const float* __restrict__ m,
                            const float* __restrict__ v, float* __restrict__ out) {
    int t = threadIdx.x;
    int n = blockIdx.x * 4 + (t >> 6);
    if (n >= NN) return;
    int l = t & 63;
    int grp = l >> 4;                    // 0..3
    int j = l & 15;                      // feature quad
    float4 acc = {0.f, 0.f, 0.f, 0.f};
    int b0 = row_ptr[n], b1 = row_ptr[n + 1];
    int e = b0 + grp;
    Entry en;
    if (e < b1) en = entries[e];
    while (e < b1) {
        int e2 = e + 4;
        Entry nx;
        if (e2 < b1) nx = entries[e2];   // prefetch next entry for this group
        float4 r = *reinterpret_cast<const float4*>(&hw[(long)en.s * HD + j * 4]);
        acc.x = fmaf(r.x, en.c, acc.x);
        acc.y = fmaf(r.y, en.c, acc.y);
        acc.z = fmaf(r.z, en.c, acc.z);
        acc.w = fmaf(r.w, en.c, acc.w);
        en = nx;
        e = e2;
    }
    // butterfly across the 4 groups (same j)
#pragma unroll
    for (int off = 16; off < 64; off <<= 1) {
        acc.x += __shfl_xor(acc.x, off, 64);
        acc.y += __shfl_xor(acc.y, off, 64);
        acc.z += __shfl_xor(acc.z, off, 64);
        acc.w += __shfl_xor(acc.w, off, 64);
    }
    if (grp == 0) {
        float di = dinv[n];
        float dd = di * di;
        float4 s4 = *reinterpret_cast<const float4*>(&hw[(long)n * HD + j * 4]);
        acc.x = fmaf(s4.x, dd, acc.x);
        acc.y = fmaf(s4.y, dd, acc.y);
        acc.z = fmaf(s4.z, dd, acc.z);
        acc.w = fmaf(s4.w, dd, acc.w);
        int f = j * 4;
        float4 gv = *reinterpret_cast<const float4*>(&g[f]);
        float4 vv = *reinterpret_cast<const float4*>(&v[f]);
        float4 bv = *reinterpret_cast<const float4*>(&bias[f]);
        float4 mv = *reinterpret_cast<const float4*>(&m[f]);
        float4 bev = *reinterpret_cast<const float4*>(&be[f]);
        float4 o;
        o.x = fmaxf((acc.x + bv.x - mv.x) * (gv.x * rsqrtf(vv.x + BN_EPS)) + bev.x, 0.f);
        o.y = fmaxf((acc.y + bv.y - mv.y) * (gv.y * rsqrtf(vv.y + BN_EPS)) + bev.y, 0.f);
        o.z = fmaxf((acc.z + bv.z - mv.z) * (gv.z * rsqrtf(vv.z + BN_EPS)) + bev.z, 0.f);
        o.w = fmaxf((acc.w + bv.w - mv.w) * (gv.w * rsqrtf(vv.w + BN_EPS)) + bev.w, 0.f);
        *reinterpret_cast<float4*>(&out[(long)n * HD + j * 4]) = o;
    }
}

// ---------------- classifier: out = h @ W_cls + b_cls ----------------
__global__ void k_cls(const float* __restrict__ h, const float* __restrict__ W,
                      const float* __restrict__ b, float* __restrict__ out) {
    __shared__ float Ws[HD * NC];
    __shared__ float bs[NC];
    int t = threadIdx.x;
    for (int i = t; i < HD * NC; i += 256) Ws[i] = W[i];
    if (t < NC) bs[t] = b[t];
    __syncthreads();
    int n = blockIdx.x * 256 + t;
    if (n >= NN) return;
    float acc[NC];
#pragma unroll
    for (int c = 0; c < NC; ++c) acc[c] = bs[c];
    const float4* hp = reinterpret_cast<const float4*>(&h[(long)n * HD]);
#pragma unroll
    for (int k4 = 0; k4 < HD / 4; ++k4) {
        float4 hv = hp[k4];
        float hh[4] = {hv.x, hv.y, hv.z, hv.w};
#pragma unroll
        for (int j = 0; j < 4; ++j) {
            int k = k4 * 4 + j;
#pragma unroll
            for (int c = 0; c < NC; ++c) acc[c] = fmaf(hh[j], Ws[k * NC + c], acc[c]);
        }
    }
#pragma unroll
    for (int c = 0; c < NC; ++c) out[(long)n * NC + c] = acc[c];
}

extern "C" void kernel_launch(void* const* d_in, const int* in_sizes, int n_in,
                              void* d_out, int out_size, void* d_ws, size_t ws_size,
                              hipStream_t stream) {
    const float* x     = (const float*)d_in[0];
    const int*   ei    = (const int*)d_in[1];
    const float* W_emb = (const float*)d_in[2];
    const float* b_emb = (const float*)d_in[3];
    const float* W1    = (const float*)d_in[4];
    const float* b1    = (const float*)d_in[5];
    const float* g1    = (const float*)d_in[6];
    const float* be1   = (const float*)d_in[7];
    const float* m1    = (const float*)d_in[8];
    const float* v1    = (const float*)d_in[9];
    const float* W2    = (const float*)d_in[10];
    const float* b2    = (const float*)d_in[11];
    const float* g2    = (const float*)d_in[12];
    const float* be2   = (const float*)d_in[13];
    const float* m2    = (const float*)d_in[14];
    const float* v2    = (const float*)d_in[15];
    const float* W_cls = (const float*)d_in[16];
    const float* b_cls = (const float*)d_in[17];
    float* out = (float*)d_out;

    const int* src = ei;          // edge_index[0]
    const int* dst = ei + NE;     // edge_index[1]

    const long NP = (NN + 511) & ~511;            // 100352
    float* dinv    = (float*)d_ws;                // NP
    int*   cnt     = (int*)(dinv + NP);           // NP (cnt, later cursor)
    int*   row_ptr = cnt + NP;                    // NP (needs N+1)
    int*   partials= row_ptr + NP;                // 1024
    Entry* entries = (Entry*)(partials + 1024);   // NE * 8B
    float* bufA    = (float*)(entries + NE);      // N*H
    float* bufB    = bufA + (long)NN * HD;        // N*H

    // ---- CSR build (once, shared by both layers) ----
    k_zero_cnt<<<SCAN_NB, SCAN_B, 0, stream>>>(cnt);
    k_hist<<<(NE + 255) / 256, 256, 0, stream>>>(dst, cnt);
    k_dinv<<<SCAN_NB, SCAN_B, 0, stream>>>(cnt, dinv);
    k_scan1<<<SCAN_NB, SCAN_B, 0, stream>>>(cnt, row_ptr, partials);
    k_scan2<<<1, 512, 0, stream>>>(partials);
    k_scan3<<<SCAN_NB, SCAN_B, 0, stream>>>(row_ptr, cnt /*cursor*/, partials);
    k_fill<<<(NE + 255) / 256, 256, 0, stream>>>(src, dst, dinv, cnt /*cursor*/, entries);

    // ---- pipeline ----
    k_embed<<<(NN + 3) / 4, 256, 0, stream>>>(x, W_emb, b_emb, bufA);

    k_gemm<<<(NN + 63) / 64, 256, 0, stream>>>(bufA, W1, bufB);
    k_gather_bn<<<(NN + 3) / 4, 256, 0, stream>>>(bufB, dinv, row_ptr, entries,
                                                  b1, g1, be1, m1, v1, bufA);

    k_gemm<<<(NN + 63) / 64, 256, 0, stream>>>(bufA, W2, bufB);
    k_gather_bn<<<(NN + 3) / 4, 256, 0, stream>>>(bufB, dinv, row_ptr, entries,
                                                  b2, g2, be2, m2, v2, bufA);

    k_cls<<<(NN + 255) / 256, 256, 0, stream>>>(bufA, W_cls, b_cls, out);
}

// Round 4
// 306.237 us; speedup vs baseline: 4.0787x; 4.0787x over previous
//
#include <hip/hip_runtime.h>

#define NN 100000      // nodes
#define NE 1200000     // edges
#define FIN 22
#define HD 64
#define NC 6
#define BN_EPS 1e-5f
#define SCAN_B 256
#define SCAN_NB ((NN + SCAN_B - 1) / SCAN_B)   // 391

struct Entry { int s; float c; };   // src node, edge coefficient

// ---------------- CSR build ----------------
__global__ void k_zero_cnt(int* __restrict__ cnt) {
    int i = blockIdx.x * blockDim.x + threadIdx.x;
    if (i < NN) cnt[i] = 0;
}

__global__ void k_hist(const int* __restrict__ dst, int* __restrict__ cnt) {
    int e = blockIdx.x * blockDim.x + threadIdx.x;
    if (e < NE) atomicAdd(&cnt[dst[e]], 1);
}

__global__ void k_dinv(const int* __restrict__ cnt, float* __restrict__ dinv) {
    int i = blockIdx.x * blockDim.x + threadIdx.x;
    if (i < NN) dinv[i] = rsqrtf((float)cnt[i] + 1.0f);  // +1 self loop
}

// exclusive scan, level 1
__global__ void k_scan1(const int* __restrict__ cnt, int* __restrict__ row_ptr,
                        int* __restrict__ partials) {
    __shared__ int s[SCAN_B];
    int t = threadIdx.x;
    int i = blockIdx.x * SCAN_B + t;
    int v = (i < NN) ? cnt[i] : 0;
    s[t] = v;
    __syncthreads();
    for (int off = 1; off < SCAN_B; off <<= 1) {
        int x = (t >= off) ? s[t - off] : 0;
        __syncthreads();
        s[t] += x;
        __syncthreads();
    }
    if (i < NN) row_ptr[i] = s[t] - v;
    if (t == SCAN_B - 1) partials[blockIdx.x] = s[t];
}

__global__ void k_scan2(int* __restrict__ partials) {
    __shared__ int s[512];
    int t = threadIdx.x;
    int v = (t < SCAN_NB) ? partials[t] : 0;
    s[t] = v;
    __syncthreads();
    for (int off = 1; off < 512; off <<= 1) {
        int x = (t >= off) ? s[t - off] : 0;
        __syncthreads();
        s[t] += x;
        __syncthreads();
    }
    if (t < SCAN_NB) partials[t] = s[t] - v;
}

__global__ void k_scan3(int* __restrict__ row_ptr, int* __restrict__ cursor,
                        const int* __restrict__ partials) {
    int i = blockIdx.x * SCAN_B + threadIdx.x;
    if (i < NN) {
        int v = row_ptr[i] + partials[blockIdx.x];
        row_ptr[i] = v;
        cursor[i] = v;
    }
    if (i == 0) row_ptr[NN] = NE;
}

__global__ void k_fill(const int* __restrict__ src, const int* __restrict__ dst,
                       const float* __restrict__ dinv, int* __restrict__ cursor,
                       Entry* __restrict__ entries) {
    int e = blockIdx.x * blockDim.x + threadIdx.x;
    if (e >= NE) return;
    int s = src[e], d = dst[e];
    int p = atomicAdd(&cursor[d], 1);
    Entry en;
    en.s = s;
    en.c = dinv[s] * dinv[d];
    entries[p] = en;
}

// ---------------- embed: h = relu(x @ W_emb + b_emb) ----------------
__global__ void k_embed(const float* __restrict__ x, const float* __restrict__ W,
                        const float* __restrict__ b, float* __restrict__ h) {
    __shared__ float Ws[FIN * HD];
    __shared__ float xs[4][FIN];
    int t = threadIdx.x;
    for (int i = t; i < FIN * HD; i += 256) Ws[i] = W[i];
    int n0 = blockIdx.x * 4;
    for (int i = t; i < 4 * FIN; i += 256) {
        int n = n0 + i / FIN;
        xs[i / FIN][i % FIN] = (n < NN) ? x[(long)n * FIN + i % FIN] : 0.f;
    }
    __syncthreads();
    int local = t >> 6;
    int f = t & 63;
    int n = n0 + local;
    if (n < NN) {
        float acc = b[f];
#pragma unroll
        for (int k = 0; k < FIN; ++k) acc = fmaf(xs[local][k], Ws[k * HD + f], acc);
        h[(long)n * HD + f] = fmaxf(acc, 0.f);
    }
}

// ---------------- layer GEMM: hw = hin @ W ----------------
// 64 nodes/block; h staged TRANSPOSED in LDS; thread = 4 nodes x 4 features.
// Inner-loop LDS reads are ds_read_b128. unroll capped at 8 to avoid VGPR
// spill (full unroll hoisted 128 b128 loads -> 1.5 GB scratch traffic, round 3).
__global__ void k_gemm(const float* __restrict__ hin, const float* __restrict__ W,
                       float* __restrict__ hw) {
    __shared__ float Ws[HD * HD];       // 16 KB, row-major [k][f]
    __shared__ float hsT[HD * 64];      // 16 KB, [k][node]
    int t = threadIdx.x;
    // stage W (1024 float4)
    for (int i = t; i < 1024; i += 256)
        reinterpret_cast<float4*>(Ws)[i] = reinterpret_cast<const float4*>(W)[i];
    int n0 = blockIdx.x * 64;
    // stage 64 h rows transposed (read float4 rows, scatter to [k][node])
    for (int i = t; i < 1024; i += 256) {
        int node = i & 63;
        int kq = i >> 6;                // 0..15
        int n = n0 + node;
        float4 val = (n < NN) ? *reinterpret_cast<const float4*>(&hin[(long)n * HD + kq * 4])
                              : make_float4(0.f, 0.f, 0.f, 0.f);
        hsT[(kq * 4 + 0) * 64 + node] = val.x;
        hsT[(kq * 4 + 1) * 64 + node] = val.y;
        hsT[(kq * 4 + 2) * 64 + node] = val.z;
        hsT[(kq * 4 + 3) * 64 + node] = val.w;
    }
    __syncthreads();
    int fq = t & 15;                    // feature quad
    int ng = t >> 4;                    // node group (0..15), nodes ng*4..+3
    float4 a0 = {0,0,0,0}, a1 = {0,0,0,0}, a2 = {0,0,0,0}, a3 = {0,0,0,0};
#pragma unroll 8
    for (int k = 0; k < HD; ++k) {
        float4 w = *reinterpret_cast<const float4*>(&Ws[k * HD + fq * 4]);
        float4 h4 = *reinterpret_cast<const float4*>(&hsT[k * 64 + ng * 4]);
        a0.x = fmaf(h4.x, w.x, a0.x); a0.y = fmaf(h4.x, w.y, a0.y);
        a0.z = fmaf(h4.x, w.z, a0.z); a0.w = fmaf(h4.x, w.w, a0.w);
        a1.x = fmaf(h4.y, w.x, a1.x); a1.y = fmaf(h4.y, w.y, a1.y);
        a1.z = fmaf(h4.y, w.z, a1.z); a1.w = fmaf(h4.y, w.w, a1.w);
        a2.x = fmaf(h4.z, w.x, a2.x); a2.y = fmaf(h4.z, w.y, a2.y);
        a2.z = fmaf(h4.z, w.z, a2.z); a2.w = fmaf(h4.z, w.w, a2.w);
        a3.x = fmaf(h4.w, w.x, a3.x); a3.y = fmaf(h4.w, w.y, a3.y);
        a3.z = fmaf(h4.w, w.z, a3.z); a3.w = fmaf(h4.w, w.w, a3.w);
    }
    int nb = n0 + ng * 4;
    if (nb + 0 < NN) *reinterpret_cast<float4*>(&hw[(long)(nb + 0) * HD + fq * 4]) = a0;
    if (nb + 1 < NN) *reinterpret_cast<float4*>(&hw[(long)(nb + 1) * HD + fq * 4]) = a1;
    if (nb + 2 < NN) *reinterpret_cast<float4*>(&hw[(long)(nb + 2) * HD + fq * 4]) = a2;
    if (nb + 3 < NN) *reinterpret_cast<float4*>(&hw[(long)(nb + 3) * HD + fq * 4]) = a3;
}

// ---------------- fused gather + self-loop + bias + BN + ReLU ----------------
// one 64-lane wave per node; 4 groups x 16 lanes; group g handles edges b0+g, b0+g+4, ...
// each lane holds float4 of features; 4 row-gathers in flight + entry prefetch.
__global__ void k_gather_bn(const float* __restrict__ hw, const float* __restrict__ dinv,
                            const int* __restrict__ row_ptr, const Entry* __restrict__ entries,
                            const float* __restrict__ bias, const float* __restrict__ g,
                            const float* __restrict__ be, const float* __restrict__ m,
                            const float* __restrict__ v, float* __restrict__ out) {
    int t = threadIdx.x;
    int n = blockIdx.x * 4 + (t >> 6);
    if (n >= NN) return;
    int l = t & 63;
    int grp = l >> 4;                    // 0..3
    int j = l & 15;                      // feature quad
    float4 acc = {0.f, 0.f, 0.f, 0.f};
    int b0 = row_ptr[n], b1 = row_ptr[n + 1];
    int e = b0 + grp;
    Entry en;
    if (e < b1) en = entries[e];
    while (e < b1) {
        int e2 = e + 4;
        Entry nx;
        if (e2 < b1) nx = entries[e2];   // prefetch next entry for this group
        float4 r = *reinterpret_cast<const float4*>(&hw[(long)en.s * HD + j * 4]);
        acc.x = fmaf(r.x, en.c, acc.x);
        acc.y = fmaf(r.y, en.c, acc.y);
        acc.z = fmaf(r.z, en.c, acc.z);
        acc.w = fmaf(r.w, en.c, acc.w);
        en = nx;
        e = e2;
    }
    // butterfly across the 4 groups (same j)
#pragma unroll
    for (int off = 16; off < 64; off <<= 1) {
        acc.x += __shfl_xor(acc.x, off, 64);
        acc.y += __shfl_xor(acc.y, off, 64);
        acc.z += __shfl_xor(acc.z, off, 64);
        acc.w += __shfl_xor(acc.w, off, 64);
    }
    if (grp == 0) {
        float di = dinv[n];
        float dd = di * di;
        float4 s4 = *reinterpret_cast<const float4*>(&hw[(long)n * HD + j * 4]);
        acc.x = fmaf(s4.x, dd, acc.x);
        acc.y = fmaf(s4.y, dd, acc.y);
        acc.z = fmaf(s4.z, dd, acc.z);
        acc.w = fmaf(s4.w, dd, acc.w);
        int f = j * 4;
        float4 gv = *reinterpret_cast<const float4*>(&g[f]);
        float4 vv = *reinterpret_cast<const float4*>(&v[f]);
        float4 bv = *reinterpret_cast<const float4*>(&bias[f]);
        float4 mv = *reinterpret_cast<const float4*>(&m[f]);
        float4 bev = *reinterpret_cast<const float4*>(&be[f]);
        float4 o;
        o.x = fmaxf((acc.x + bv.x - mv.x) * (gv.x * rsqrtf(vv.x + BN_EPS)) + bev.x, 0.f);
        o.y = fmaxf((acc.y + bv.y - mv.y) * (gv.y * rsqrtf(vv.y + BN_EPS)) + bev.y, 0.f);
        o.z = fmaxf((acc.z + bv.z - mv.z) * (gv.z * rsqrtf(vv.z + BN_EPS)) + bev.z, 0.f);
        o.w = fmaxf((acc.w + bv.w - mv.w) * (gv.w * rsqrtf(vv.w + BN_EPS)) + bev.w, 0.f);
        *reinterpret_cast<float4*>(&out[(long)n * HD + j * 4]) = o;
    }
}

// ---------------- classifier: out = h @ W_cls + b_cls ----------------
__global__ void k_cls(const float* __restrict__ h, const float* __restrict__ W,
                      const float* __restrict__ b, float* __restrict__ out) {
    __shared__ float Ws[HD * NC];
    __shared__ float bs[NC];
    int t = threadIdx.x;
    for (int i = t; i < HD * NC; i += 256) Ws[i] = W[i];
    if (t < NC) bs[t] = b[t];
    __syncthreads();
    int n = blockIdx.x * 256 + t;
    if (n >= NN) return;
    float acc[NC];
#pragma unroll
    for (int c = 0; c < NC; ++c) acc[c] = bs[c];
    const float4* hp = reinterpret_cast<const float4*>(&h[(long)n * HD]);
#pragma unroll
    for (int k4 = 0; k4 < HD / 4; ++k4) {
        float4 hv = hp[k4];
        float hh[4] = {hv.x, hv.y, hv.z, hv.w};
#pragma unroll
        for (int j = 0; j < 4; ++j) {
            int k = k4 * 4 + j;
#pragma unroll
            for (int c = 0; c < NC; ++c) acc[c] = fmaf(hh[j], Ws[k * NC + c], acc[c]);
        }
    }
#pragma unroll
    for (int c = 0; c < NC; ++c) out[(long)n * NC + c] = acc[c];
}

extern "C" void kernel_launch(void* const* d_in, const int* in_sizes, int n_in,
                              void* d_out, int out_size, void* d_ws, size_t ws_size,
                              hipStream_t stream) {
    const float* x     = (const float*)d_in[0];
    const int*   ei    = (const int*)d_in[1];
    const float* W_emb = (const float*)d_in[2];
    const float* b_emb = (const float*)d_in[3];
    const float* W1    = (const float*)d_in[4];
    const float* b1    = (const float*)d_in[5];
    const float* g1    = (const float*)d_in[6];
    const float* be1   = (const float*)d_in[7];
    const float* m1    = (const float*)d_in[8];
    const float* v1    = (const float*)d_in[9];
    const float* W2    = (const float*)d_in[10];
    const float* b2    = (const float*)d_in[11];
    const float* g2    = (const float*)d_in[12];
    const float* be2   = (const float*)d_in[13];
    const float* m2    = (const float*)d_in[14];
    const float* v2    = (const float*)d_in[15];
    const float* W_cls = (const float*)d_in[16];
    const float* b_cls = (const float*)d_in[17];
    float* out = (float*)d_out;

    const int* src = ei;          // edge_index[0]
    const int* dst = ei + NE;     // edge_index[1]

    const long NP = (NN + 511) & ~511;            // 100352
    float* dinv    = (float*)d_ws;                // NP
    int*   cnt     = (int*)(dinv + NP);           // NP (cnt, later cursor)
    int*   row_ptr = cnt + NP;                    // NP (needs N+1)
    int*   partials= row_ptr + NP;                // 1024
    Entry* entries = (Entry*)(partials + 1024);   // NE * 8B
    float* bufA    = (float*)(entries + NE);      // N*H
    float* bufB    = bufA + (long)NN * HD;        // N*H

    // ---- CSR build (once, shared by both layers) ----
    k_zero_cnt<<<SCAN_NB, SCAN_B, 0, stream>>>(cnt);
    k_hist<<<(NE + 255) / 256, 256, 0, stream>>>(dst, cnt);
    k_dinv<<<SCAN_NB, SCAN_B, 0, stream>>>(cnt, dinv);
    k_scan1<<<SCAN_NB, SCAN_B, 0, stream>>>(cnt, row_ptr, partials);
    k_scan2<<<1, 512, 0, stream>>>(partials);
    k_scan3<<<SCAN_NB, SCAN_B, 0, stream>>>(row_ptr, cnt /*cursor*/, partials);
    k_fill<<<(NE + 255) / 256, 256, 0, stream>>>(src, dst, dinv, cnt /*cursor*/, entries);

    // ---- pipeline ----
    k_embed<<<(NN + 3) / 4, 256, 0, stream>>>(x, W_emb, b_emb, bufA);

    k_gemm<<<(NN + 63) / 64, 256, 0, stream>>>(bufA, W1, bufB);
    k_gather_bn<<<(NN + 3) / 4, 256, 0, stream>>>(bufB, dinv, row_ptr, entries,
                                                  b1, g1, be1, m1, v1, bufA);

    k_gemm<<<(NN + 63) / 64, 256, 0, stream>>>(bufA, W2, bufB);
    k_gather_bn<<<(NN + 3) / 4, 256, 0, stream>>>(bufB, dinv, row_ptr, entries,
                                                  b2, g2, be2, m2, v2, bufA);

    k_cls<<<(NN + 255) / 256, 256, 0, stream>>>(bufA, W_cls, b_cls, out);
}

// Round 5
// 274.934 us; speedup vs baseline: 4.5430x; 1.1139x over previous
//
#include <hip/hip_runtime.h>

#define NN 100000      // nodes
#define NE 1200000     // edges
#define FIN 22
#define HD 64
#define NC 6
#define BN_EPS 1e-5f
#define SCAN_B 256
#define SCAN_NB ((NN + SCAN_B - 1) / SCAN_B)   // 391
#define HIST_NB ((NE + 255) / 256)             // 4688
#define EMB_NB  ((NN + 3) / 4)                 // 25000
#define GEMM_NB ((NN + 63) / 64)               // 1563

// ---------------- zero counts ----------------
__global__ void k_zero_cnt(int* __restrict__ cnt) {
    int i = blockIdx.x * blockDim.x + threadIdx.x;
    if (i < NN) cnt[i] = 0;
}

// ---------------- fused: hist (rank-recording) || embed ----------------
// hist blocks: rank[e] = old count of dst  (atomic, coalesced rank write)
// embed blocks: h = relu(x @ W_emb + b_emb)
__global__ void k_hist_embed(const int* __restrict__ dst, int* __restrict__ cnt,
                             int* __restrict__ rank,
                             const float* __restrict__ x, const float* __restrict__ W,
                             const float* __restrict__ b, float* __restrict__ h) {
    __shared__ float Ws[FIN * HD];
    __shared__ float xs[4][FIN];
    if (blockIdx.x < HIST_NB) {
        int e = blockIdx.x * 256 + threadIdx.x;
        if (e < NE) rank[e] = atomicAdd(&cnt[dst[e]], 1);
        return;
    }
    int bid = blockIdx.x - HIST_NB;
    int t = threadIdx.x;
    for (int i = t; i < FIN * HD; i += 256) Ws[i] = W[i];
    int n0 = bid * 4;
    for (int i = t; i < 4 * FIN; i += 256) {
        int n = n0 + i / FIN;
        xs[i / FIN][i % FIN] = (n < NN) ? x[(long)n * FIN + i % FIN] : 0.f;
    }
    __syncthreads();
    int local = t >> 6;
    int f = t & 63;
    int n = n0 + local;
    if (n < NN) {
        float acc = b[f];
#pragma unroll
        for (int k = 0; k < FIN; ++k) acc = fmaf(xs[local][k], Ws[k * HD + f], acc);
        h[(long)n * HD + f] = fmaxf(acc, 0.f);
    }
}

// ---------------- fused: dinv + scan level 1 ----------------
__global__ void k_dinv_scan1(const int* __restrict__ cnt, float* __restrict__ dinv,
                             int* __restrict__ row_ptr, int* __restrict__ partials) {
    __shared__ int s[SCAN_B];
    int t = threadIdx.x;
    int i = blockIdx.x * SCAN_B + t;
    int v = (i < NN) ? cnt[i] : 0;
    if (i < NN) dinv[i] = rsqrtf((float)v + 1.0f);   // +1 self loop
    s[t] = v;
    __syncthreads();
    for (int off = 1; off < SCAN_B; off <<= 1) {
        int x = (t >= off) ? s[t - off] : 0;
        __syncthreads();
        s[t] += x;
        __syncthreads();
    }
    if (i < NN) row_ptr[i] = s[t] - v;
    if (t == SCAN_B - 1) partials[blockIdx.x] = s[t];
}

__global__ void k_scan2(int* __restrict__ partials) {
    __shared__ int s[512];
    int t = threadIdx.x;
    int v = (t < SCAN_NB) ? partials[t] : 0;
    s[t] = v;
    __syncthreads();
    for (int off = 1; off < 512; off <<= 1) {
        int x = (t >= off) ? s[t - off] : 0;
        __syncthreads();
        s[t] += x;
        __syncthreads();
    }
    if (t < SCAN_NB) partials[t] = s[t] - v;
}

__global__ void k_scan3(int* __restrict__ row_ptr, const int* __restrict__ partials) {
    int i = blockIdx.x * SCAN_B + threadIdx.x;
    if (i < NN) row_ptr[i] += partials[blockIdx.x];
    if (i == 0) row_ptr[NN] = NE;
}

// ---------------- fused: fill (atomic-free) || gemm layer1 ----------------
// fill: ent[row_ptr[d] + rank[e]] = src[e]  (4B scatter, no atomics)
// gemm: hw = hin @ W  (64 nodes/block, transposed h in LDS, unroll-capped)
__global__ void k_fill_gemm(const int* __restrict__ src, const int* __restrict__ dst,
                            const int* __restrict__ rank, const int* __restrict__ row_ptr,
                            int* __restrict__ ent,
                            const float* __restrict__ hin, const float* __restrict__ W,
                            float* __restrict__ hw) {
    __shared__ float Ws[HD * HD];       // 16 KB
    __shared__ float hsT[HD * 64];      // 16 KB
    if (blockIdx.x < HIST_NB) {
        int e = blockIdx.x * 256 + threadIdx.x;
        if (e < NE) {
            int d = dst[e];
            ent[row_ptr[d] + rank[e]] = src[e];
        }
        return;
    }
    int t = threadIdx.x;
    for (int i = t; i < 1024; i += 256)
        reinterpret_cast<float4*>(Ws)[i] = reinterpret_cast<const float4*>(W)[i];
    int n0 = (blockIdx.x - HIST_NB) * 64;
    for (int i = t; i < 1024; i += 256) {
        int node = i & 63;
        int kq = i >> 6;
        int n = n0 + node;
        float4 val = (n < NN) ? *reinterpret_cast<const float4*>(&hin[(long)n * HD + kq * 4])
                              : make_float4(0.f, 0.f, 0.f, 0.f);
        hsT[(kq * 4 + 0) * 64 + node] = val.x;
        hsT[(kq * 4 + 1) * 64 + node] = val.y;
        hsT[(kq * 4 + 2) * 64 + node] = val.z;
        hsT[(kq * 4 + 3) * 64 + node] = val.w;
    }
    __syncthreads();
    int fq = t & 15;
    int ng = t >> 4;
    float4 a0 = {0,0,0,0}, a1 = {0,0,0,0}, a2 = {0,0,0,0}, a3 = {0,0,0,0};
#pragma unroll 8
    for (int k = 0; k < HD; ++k) {
        float4 w = *reinterpret_cast<const float4*>(&Ws[k * HD + fq * 4]);
        float4 h4 = *reinterpret_cast<const float4*>(&hsT[k * 64 + ng * 4]);
        a0.x = fmaf(h4.x, w.x, a0.x); a0.y = fmaf(h4.x, w.y, a0.y);
        a0.z = fmaf(h4.x, w.z, a0.z); a0.w = fmaf(h4.x, w.w, a0.w);
        a1.x = fmaf(h4.y, w.x, a1.x); a1.y = fmaf(h4.y, w.y, a1.y);
        a1.z = fmaf(h4.y, w.z, a1.z); a1.w = fmaf(h4.y, w.w, a1.w);
        a2.x = fmaf(h4.z, w.x, a2.x); a2.y = fmaf(h4.z, w.y, a2.y);
        a2.z = fmaf(h4.z, w.z, a2.z); a2.w = fmaf(h4.z, w.w, a2.w);
        a3.x = fmaf(h4.w, w.x, a3.x); a3.y = fmaf(h4.w, w.y, a3.y);
        a3.z = fmaf(h4.w, w.z, a3.z); a3.w = fmaf(h4.w, w.w, a3.w);
    }
    int nb = n0 + ng * 4;
    if (nb + 0 < NN) *reinterpret_cast<float4*>(&hw[(long)(nb + 0) * HD + fq * 4]) = a0;
    if (nb + 1 < NN) *reinterpret_cast<float4*>(&hw[(long)(nb + 1) * HD + fq * 4]) = a1;
    if (nb + 2 < NN) *reinterpret_cast<float4*>(&hw[(long)(nb + 2) * HD + fq * 4]) = a2;
    if (nb + 3 < NN) *reinterpret_cast<float4*>(&hw[(long)(nb + 3) * HD + fq * 4]) = a3;
}

// ---------------- plain gemm (layer 2) ----------------
__global__ void k_gemm(const float* __restrict__ hin, const float* __restrict__ W,
                       float* __restrict__ hw) {
    __shared__ float Ws[HD * HD];
    __shared__ float hsT[HD * 64];
    int t = threadIdx.x;
    for (int i = t; i < 1024; i += 256)
        reinterpret_cast<float4*>(Ws)[i] = reinterpret_cast<const float4*>(W)[i];
    int n0 = blockIdx.x * 64;
    for (int i = t; i < 1024; i += 256) {
        int node = i & 63;
        int kq = i >> 6;
        int n = n0 + node;
        float4 val = (n < NN) ? *reinterpret_cast<const float4*>(&hin[(long)n * HD + kq * 4])
                              : make_float4(0.f, 0.f, 0.f, 0.f);
        hsT[(kq * 4 + 0) * 64 + node] = val.x;
        hsT[(kq * 4 + 1) * 64 + node] = val.y;
        hsT[(kq * 4 + 2) * 64 + node] = val.z;
        hsT[(kq * 4 + 3) * 64 + node] = val.w;
    }
    __syncthreads();
    int fq = t & 15;
    int ng = t >> 4;
    float4 a0 = {0,0,0,0}, a1 = {0,0,0,0}, a2 = {0,0,0,0}, a3 = {0,0,0,0};
#pragma unroll 8
    for (int k = 0; k < HD; ++k) {
        float4 w = *reinterpret_cast<const float4*>(&Ws[k * HD + fq * 4]);
        float4 h4 = *reinterpret_cast<const float4*>(&hsT[k * 64 + ng * 4]);
        a0.x = fmaf(h4.x, w.x, a0.x); a0.y = fmaf(h4.x, w.y, a0.y);
        a0.z = fmaf(h4.x, w.z, a0.z); a0.w = fmaf(h4.x, w.w, a0.w);
        a1.x = fmaf(h4.y, w.x, a1.x); a1.y = fmaf(h4.y, w.y, a1.y);
        a1.z = fmaf(h4.y, w.z, a1.z); a1.w = fmaf(h4.y, w.w, a1.w);
        a2.x = fmaf(h4.z, w.x, a2.x); a2.y = fmaf(h4.z, w.y, a2.y);
        a2.z = fmaf(h4.z, w.z, a2.z); a2.w = fmaf(h4.z, w.w, a2.w);
        a3.x = fmaf(h4.w, w.x, a3.x); a3.y = fmaf(h4.w, w.y, a3.y);
        a3.z = fmaf(h4.w, w.z, a3.z); a3.w = fmaf(h4.w, w.w, a3.w);
    }
    int nb = n0 + ng * 4;
    if (nb + 0 < NN) *reinterpret_cast<float4*>(&hw[(long)(nb + 0) * HD + fq * 4]) = a0;
    if (nb + 1 < NN) *reinterpret_cast<float4*>(&hw[(long)(nb + 1) * HD + fq * 4]) = a1;
    if (nb + 2 < NN) *reinterpret_cast<float4*>(&hw[(long)(nb + 2) * HD + fq * 4]) = a2;
    if (nb + 3 < NN) *reinterpret_cast<float4*>(&hw[(long)(nb + 3) * HD + fq * 4]) = a3;
}

// ---------------- gather + self-loop + bias + BN + ReLU (+ optional classifier) ----------------
// one wave per node; 4 groups x 16 lanes; ent is 4B (src only), coef from dinv.
template <int WITH_CLS>
__global__ void k_gather_bn_t(const float* __restrict__ hw, const float* __restrict__ dinv,
                              const int* __restrict__ row_ptr, const int* __restrict__ ent,
                              const float* __restrict__ bias, const float* __restrict__ g,
                              const float* __restrict__ be, const float* __restrict__ m,
                              const float* __restrict__ v, float* __restrict__ out,
                              const float* __restrict__ Wc, const float* __restrict__ bc) {
    int t = threadIdx.x;
    int n = blockIdx.x * 4 + (t >> 6);
    if (n >= NN) return;
    int l = t & 63;
    int grp = l >> 4;
    int j = l & 15;
    float di = dinv[n];
    float4 acc = {0.f, 0.f, 0.f, 0.f};
    int b0 = row_ptr[n], b1 = row_ptr[n + 1];
    int e = b0 + grp;
    int s = 0; float dv = 0.f;
    if (e < b1) { s = ent[e]; dv = dinv[s]; }
    while (e < b1) {
        int e2 = e + 4;
        int sn = 0; float dvn = 0.f;
        if (e2 < b1) { sn = ent[e2]; dvn = dinv[sn]; }   // prefetch next
        float c = dv * di;
        float4 r = *reinterpret_cast<const float4*>(&hw[(long)s * HD + j * 4]);
        acc.x = fmaf(r.x, c, acc.x);
        acc.y = fmaf(r.y, c, acc.y);
        acc.z = fmaf(r.z, c, acc.z);
        acc.w = fmaf(r.w, c, acc.w);
        s = sn; dv = dvn; e = e2;
    }
#pragma unroll
    for (int off = 16; off < 64; off <<= 1) {
        acc.x += __shfl_xor(acc.x, off, 64);
        acc.y += __shfl_xor(acc.y, off, 64);
        acc.z += __shfl_xor(acc.z, off, 64);
        acc.w += __shfl_xor(acc.w, off, 64);
    }
    if (grp == 0) {
        float dd = di * di;
        float4 s4 = *reinterpret_cast<const float4*>(&hw[(long)n * HD + j * 4]);
        acc.x = fmaf(s4.x, dd, acc.x);
        acc.y = fmaf(s4.y, dd, acc.y);
        acc.z = fmaf(s4.z, dd, acc.z);
        acc.w = fmaf(s4.w, dd, acc.w);
        int f = j * 4;
        float4 gv = *reinterpret_cast<const float4*>(&g[f]);
        float4 vv = *reinterpret_cast<const float4*>(&v[f]);
        float4 bv = *reinterpret_cast<const float4*>(&bias[f]);
        float4 mv = *reinterpret_cast<const float4*>(&m[f]);
        float4 bev = *reinterpret_cast<const float4*>(&be[f]);
        float4 o;
        o.x = fmaxf((acc.x + bv.x - mv.x) * (gv.x * rsqrtf(vv.x + BN_EPS)) + bev.x, 0.f);
        o.y = fmaxf((acc.y + bv.y - mv.y) * (gv.y * rsqrtf(vv.y + BN_EPS)) + bev.y, 0.f);
        o.z = fmaxf((acc.z + bv.z - mv.z) * (gv.z * rsqrtf(vv.z + BN_EPS)) + bev.z, 0.f);
        o.w = fmaxf((acc.w + bv.w - mv.w) * (gv.w * rsqrtf(vv.w + BN_EPS)) + bev.w, 0.f);
        if (WITH_CLS == 0) {
            *reinterpret_cast<float4*>(&out[(long)n * HD + j * 4]) = o;
        } else {
            // classifier epilogue: lane j covers k = 4j..4j+3 of h
            float accC[NC];
#pragma unroll
            for (int c = 0; c < NC; ++c) {
                accC[c] = o.x * Wc[(4 * j + 0) * NC + c]
                        + o.y * Wc[(4 * j + 1) * NC + c]
                        + o.z * Wc[(4 * j + 2) * NC + c]
                        + o.w * Wc[(4 * j + 3) * NC + c];
            }
#pragma unroll
            for (int off = 1; off < 16; off <<= 1) {
#pragma unroll
                for (int c = 0; c < NC; ++c) accC[c] += __shfl_xor(accC[c], off, 64);
            }
            if (j == 0) {
#pragma unroll
                for (int c = 0; c < NC; ++c) out[(long)n * NC + c] = accC[c] + bc[c];
            }
        }
    }
}

extern "C" void kernel_launch(void* const* d_in, const int* in_sizes, int n_in,
                              void* d_out, int out_size, void* d_ws, size_t ws_size,
                              hipStream_t stream) {
    const float* x     = (const float*)d_in[0];
    const int*   ei    = (const int*)d_in[1];
    const float* W_emb = (const float*)d_in[2];
    const float* b_emb = (const float*)d_in[3];
    const float* W1    = (const float*)d_in[4];
    const float* b1    = (const float*)d_in[5];
    const float* g1    = (const float*)d_in[6];
    const float* be1   = (const float*)d_in[7];
    const float* m1    = (const float*)d_in[8];
    const float* v1    = (const float*)d_in[9];
    const float* W2    = (const float*)d_in[10];
    const float* b2    = (const float*)d_in[11];
    const float* g2    = (const float*)d_in[12];
    const float* be2   = (const float*)d_in[13];
    const float* m2    = (const float*)d_in[14];
    const float* v2    = (const float*)d_in[15];
    const float* W_cls = (const float*)d_in[16];
    const float* b_cls = (const float*)d_in[17];
    float* out = (float*)d_out;

    const int* src = ei;          // edge_index[0]
    const int* dst = ei + NE;     // edge_index[1]

    const long NP = (NN + 511) & ~511;            // 100352
    float* dinv    = (float*)d_ws;                // NP
    int*   cnt     = (int*)(dinv + NP);           // NP
    int*   row_ptr = cnt + NP;                    // NP (N+1 fits)
    int*   partials= row_ptr + NP;                // 1024
    int*   rank    = partials + 1024;             // NE
    int*   ent     = rank + NE;                   // NE
    float* bufA    = (float*)(ent + NE);          // N*H
    float* bufB    = bufA + (long)NN * HD;        // N*H

    // CSR build + embed (overlapped)
    k_zero_cnt<<<SCAN_NB, SCAN_B, 0, stream>>>(cnt);
    k_hist_embed<<<HIST_NB + EMB_NB, 256, 0, stream>>>(dst, cnt, rank, x, W_emb, b_emb, bufA);
    k_dinv_scan1<<<SCAN_NB, SCAN_B, 0, stream>>>(cnt, dinv, row_ptr, partials);
    k_scan2<<<1, 512, 0, stream>>>(partials);
    k_scan3<<<SCAN_NB, SCAN_B, 0, stream>>>(row_ptr, partials);

    // fill (atomic-free) || gemm layer 1
    k_fill_gemm<<<HIST_NB + GEMM_NB, 256, 0, stream>>>(src, dst, rank, row_ptr, ent,
                                                       bufA, W1, bufB);
    // gather layer 1 -> bufA
    k_gather_bn_t<0><<<(NN + 3) / 4, 256, 0, stream>>>(bufB, dinv, row_ptr, ent,
                                                       b1, g1, be1, m1, v1, bufA,
                                                       nullptr, nullptr);
    // gemm layer 2
    k_gemm<<<GEMM_NB, 256, 0, stream>>>(bufA, W2, bufB);
    // gather layer 2 + BN + ReLU + classifier -> out
    k_gather_bn_t<1><<<(NN + 3) / 4, 256, 0, stream>>>(bufB, dinv, row_ptr, ent,
                                                       b2, g2, be2, m2, v2, out,
                                                       W_cls, b_cls);
}

// Round 10
// 273.376 us; speedup vs baseline: 4.5689x; 1.0057x over previous
//
#include <hip/hip_runtime.h>
#include <hip/hip_fp16.h>

#define NN 100000      // nodes
#define NE 1200000     // edges
#define FIN 22
#define HD 64
#define NC 6
#define BN_EPS 1e-5f
#define SCAN_B 256
#define SCAN_NB ((NN + SCAN_B - 1) / SCAN_B)   // 391
#define HIST_NB ((NE + 255) / 256)             // 4688
#define EMB_NB  ((NN + 3) / 4)                 // 25000
#define GEMM_NB ((NN + 63) / 64)               // 1563

// ---------------- fused: hist (rank-recording) || embed ----------------
__global__ void k_hist_embed(const int* __restrict__ dst, int* __restrict__ cnt,
                             int* __restrict__ rank,
                             const float* __restrict__ x, const float* __restrict__ W,
                             const float* __restrict__ b, float* __restrict__ h) {
    __shared__ float Ws[FIN * HD];
    __shared__ float xs[4][FIN];
    if (blockIdx.x < HIST_NB) {
        int e = blockIdx.x * 256 + threadIdx.x;
        if (e < NE) rank[e] = atomicAdd(&cnt[dst[e]], 1);
        return;
    }
    int bid = blockIdx.x - HIST_NB;
    int t = threadIdx.x;
    for (int i = t; i < FIN * HD; i += 256) Ws[i] = W[i];
    int n0 = bid * 4;
    for (int i = t; i < 4 * FIN; i += 256) {
        int n = n0 + i / FIN;
        xs[i / FIN][i % FIN] = (n < NN) ? x[(long)n * FIN + i % FIN] : 0.f;
    }
    __syncthreads();
    int local = t >> 6;
    int f = t & 63;
    int n = n0 + local;
    if (n < NN) {
        float acc = b[f];
#pragma unroll
        for (int k = 0; k < FIN; ++k) acc = fmaf(xs[local][k], Ws[k * HD + f], acc);
        h[(long)n * HD + f] = fmaxf(acc, 0.f);
    }
}

// ---------------- gemm body: hw(fp16) = hin(f32) @ W ----------------
// 64 nodes per tile; h staged transposed in LDS; unroll capped at 8 (VGPR spill
// at full unroll caused 1.5 GB scratch traffic in round 3).
__device__ __forceinline__ void gemm_tile(int n0, int t,
                                          const float* __restrict__ hin,
                                          const float* __restrict__ W,
                                          __half* __restrict__ hw,
                                          float* Ws, float* hsT) {
    for (int i = t; i < 1024; i += 256)
        reinterpret_cast<float4*>(Ws)[i] = reinterpret_cast<const float4*>(W)[i];
    for (int i = t; i < 1024; i += 256) {
        int node = i & 63;
        int kq = i >> 6;
        int n = n0 + node;
        float4 val = (n < NN) ? *reinterpret_cast<const float4*>(&hin[(long)n * HD + kq * 4])
                              : make_float4(0.f, 0.f, 0.f, 0.f);
        hsT[(kq * 4 + 0) * 64 + node] = val.x;
        hsT[(kq * 4 + 1) * 64 + node] = val.y;
        hsT[(kq * 4 + 2) * 64 + node] = val.z;
        hsT[(kq * 4 + 3) * 64 + node] = val.w;
    }
    __syncthreads();
    int fq = t & 15;
    int ng = t >> 4;
    float4 a0 = {0,0,0,0}, a1 = {0,0,0,0}, a2 = {0,0,0,0}, a3 = {0,0,0,0};
#pragma unroll 8
    for (int k = 0; k < HD; ++k) {
        float4 w = *reinterpret_cast<const float4*>(&Ws[k * HD + fq * 4]);
        float4 h4 = *reinterpret_cast<const float4*>(&hsT[k * 64 + ng * 4]);
        a0.x = fmaf(h4.x, w.x, a0.x); a0.y = fmaf(h4.x, w.y, a0.y);
        a0.z = fmaf(h4.x, w.z, a0.z); a0.w = fmaf(h4.x, w.w, a0.w);
        a1.x = fmaf(h4.y, w.x, a1.x); a1.y = fmaf(h4.y, w.y, a1.y);
        a1.z = fmaf(h4.y, w.z, a1.z); a1.w = fmaf(h4.y, w.w, a1.w);
        a2.x = fmaf(h4.z, w.x, a2.x); a2.y = fmaf(h4.z, w.y, a2.y);
        a2.z = fmaf(h4.z, w.z, a2.z); a2.w = fmaf(h4.z, w.w, a2.w);
        a3.x = fmaf(h4.w, w.x, a3.x); a3.y = fmaf(h4.w, w.y, a3.y);
        a3.z = fmaf(h4.w, w.z, a3.z); a3.w = fmaf(h4.w, w.w, a3.w);
    }
    int nb = n0 + ng * 4;
    float4 accs[4] = {a0, a1, a2, a3};
#pragma unroll
    for (int q = 0; q < 4; ++q) {
        if (nb + q < NN) {
            __half2 lo = __floats2half2_rn(accs[q].x, accs[q].y);
            __half2 hi = __floats2half2_rn(accs[q].z, accs[q].w);
            int2 pk;
            pk.x = *reinterpret_cast<int*>(&lo);
            pk.y = *reinterpret_cast<int*>(&hi);
            *reinterpret_cast<int2*>(&hw[(long)(nb + q) * HD + fq * 4]) = pk;
        }
    }
}

// ---------------- fused: dinv + scan level 1 || gemm layer 1 ----------------
__global__ void k_scan1_gemm1(const int* __restrict__ cnt, float* __restrict__ dinv,
                              int* __restrict__ row_ptr, int* __restrict__ partials,
                              const float* __restrict__ hin, const float* __restrict__ W,
                              __half* __restrict__ hw) {
    __shared__ float Ws[HD * HD];       // 16 KB
    __shared__ float hsT[HD * 64];      // 16 KB
    __shared__ int s[SCAN_B];
    if (blockIdx.x < SCAN_NB) {
        int t = threadIdx.x;
        int i = blockIdx.x * SCAN_B + t;
        int v = (i < NN) ? cnt[i] : 0;
        if (i < NN) dinv[i] = rsqrtf((float)v + 1.0f);   // +1 self loop
        s[t] = v;
        __syncthreads();
        for (int off = 1; off < SCAN_B; off <<= 1) {
            int x = (t >= off) ? s[t - off] : 0;
            __syncthreads();
            s[t] += x;
            __syncthreads();
        }
        if (i <= NN) row_ptr[i] = s[t] - v;              // local exclusive (incl. i==NN)
        if (t == SCAN_B - 1) partials[blockIdx.x] = s[t];
        return;
    }
    gemm_tile((blockIdx.x - SCAN_NB) * 64, threadIdx.x, hin, W, hw, Ws, hsT);
}

__global__ void k_scan2(int* __restrict__ partials) {
    __shared__ int s[512];
    int t = threadIdx.x;
    int v = (t < SCAN_NB) ? partials[t] : 0;
    s[t] = v;
    __syncthreads();
    for (int off = 1; off < 512; off <<= 1) {
        int x = (t >= off) ? s[t - off] : 0;
        __syncthreads();
        s[t] += x;
        __syncthreads();
    }
    if (t < SCAN_NB) partials[t] = s[t] - v;             // exclusive block offsets
}

// ---------------- fill (atomic-free, partials inline) ----------------
__global__ void k_fill(const int* __restrict__ src, const int* __restrict__ dst,
                       const int* __restrict__ rank, const int* __restrict__ row_ptr,
                       const int* __restrict__ part, int* __restrict__ ent) {
    int e = blockIdx.x * 256 + threadIdx.x;
    if (e < NE) {
        int d = dst[e];
        ent[row_ptr[d] + part[d >> 8] + rank[e]] = src[e];
    }
}

// ---------------- layer-2 gemm ----------------
__global__ void k_gemm(const float* __restrict__ hin, const float* __restrict__ W,
                       __half* __restrict__ hw) {
    __shared__ float Ws[HD * HD];
    __shared__ float hsT[HD * 64];
    gemm_tile(blockIdx.x * 64, threadIdx.x, hin, W, hw, Ws, hsT);
}

// ---------------- gather + self-loop + bias + BN + ReLU (+ optional classifier) ----------------
// one wave per node; 4 groups x 16 lanes; hw is fp16 (8B/lane row reads).
template <int WITH_CLS>
__global__ void k_gather_bn_t(const __half* __restrict__ hw, const float* __restrict__ dinv,
                              const int* __restrict__ row_ptr, const int* __restrict__ part,
                              const int* __restrict__ ent,
                              const float* __restrict__ bias, const float* __restrict__ g,
                              const float* __restrict__ be, const float* __restrict__ m,
                              const float* __restrict__ v, float* __restrict__ out,
                              const float* __restrict__ Wc, const float* __restrict__ bc) {
    int t = threadIdx.x;
    int n = blockIdx.x * 4 + (t >> 6);
    if (n >= NN) return;
    int l = t & 63;
    int grp = l >> 4;
    int j = l & 15;
    float di = dinv[n];
    float4 acc = {0.f, 0.f, 0.f, 0.f};
    int b0 = row_ptr[n] + part[n >> 8];
    int b1 = row_ptr[n + 1] + part[(n + 1) >> 8];
    int e = b0 + grp;
    int s = 0; float dv = 0.f;
    if (e < b1) { s = ent[e]; dv = dinv[s]; }
    while (e < b1) {
        int e2 = e + 4;
        int sn = 0; float dvn = 0.f;
        if (e2 < b1) { sn = ent[e2]; dvn = dinv[sn]; }   // prefetch next
        float c = dv * di;
        int2 rv = *reinterpret_cast<const int2*>(&hw[(long)s * HD + j * 4]);
        float2 f0 = __half22float2(*reinterpret_cast<__half2*>(&rv.x));
        float2 f1 = __half22float2(*reinterpret_cast<__half2*>(&rv.y));
        acc.x = fmaf(f0.x, c, acc.x);
        acc.y = fmaf(f0.y, c, acc.y);
        acc.z = fmaf(f1.x, c, acc.z);
        acc.w = fmaf(f1.y, c, acc.w);
        s = sn; dv = dvn; e = e2;
    }
#pragma unroll
    for (int off = 16; off < 64; off <<= 1) {
        acc.x += __shfl_xor(acc.x, off, 64);
        acc.y += __shfl_xor(acc.y, off, 64);
        acc.z += __shfl_xor(acc.z, off, 64);
        acc.w += __shfl_xor(acc.w, off, 64);
    }
    if (grp == 0) {
        float dd = di * di;
        int2 sv = *reinterpret_cast<const int2*>(&hw[(long)n * HD + j * 4]);
        float2 s0 = __half22float2(*reinterpret_cast<__half2*>(&sv.x));
        float2 s1 = __half22float2(*reinterpret_cast<__half2*>(&sv.y));
        acc.x = fmaf(s0.x, dd, acc.x);
        acc.y = fmaf(s0.y, dd, acc.y);
        acc.z = fmaf(s1.x, dd, acc.z);
        acc.w = fmaf(s1.y, dd, acc.w);
        int f = j * 4;
        float4 gv = *reinterpret_cast<const float4*>(&g[f]);
        float4 vv = *reinterpret_cast<const float4*>(&v[f]);
        float4 bv = *reinterpret_cast<const float4*>(&bias[f]);
        float4 mv = *reinterpret_cast<const float4*>(&m[f]);
        float4 bev = *reinterpret_cast<const float4*>(&be[f]);
        float4 o;
        o.x = fmaxf((acc.x + bv.x - mv.x) * (gv.x * rsqrtf(vv.x + BN_EPS)) + bev.x, 0.f);
        o.y = fmaxf((acc.y + bv.y - mv.y) * (gv.y * rsqrtf(vv.y + BN_EPS)) + bev.y, 0.f);
        o.z = fmaxf((acc.z + bv.z - mv.z) * (gv.z * rsqrtf(vv.z + BN_EPS)) + bev.z, 0.f);
        o.w = fmaxf((acc.w + bv.w - mv.w) * (gv.w * rsqrtf(vv.w + BN_EPS)) + bev.w, 0.f);
        if (WITH_CLS == 0) {
            *reinterpret_cast<float4*>(&out[(long)n * HD + j * 4]) = o;
        } else {
            float accC[NC];
#pragma unroll
            for (int c = 0; c < NC; ++c) {
                accC[c] = o.x * Wc[(4 * j + 0) * NC + c]
                        + o.y * Wc[(4 * j + 1) * NC + c]
                        + o.z * Wc[(4 * j + 2) * NC + c]
                        + o.w * Wc[(4 * j + 3) * NC + c];
            }
#pragma unroll
            for (int off = 1; off < 16; off <<= 1) {
#pragma unroll
                for (int c = 0; c < NC; ++c) accC[c] += __shfl_xor(accC[c], off, 64);
            }
            if (j == 0) {
#pragma unroll
                for (int c = 0; c < NC; ++c) out[(long)n * NC + c] = accC[c] + bc[c];
            }
        }
    }
}

extern "C" void kernel_launch(void* const* d_in, const int* in_sizes, int n_in,
                              void* d_out, int out_size, void* d_ws, size_t ws_size,
                              hipStream_t stream) {
    const float* x     = (const float*)d_in[0];
    const int*   ei    = (const int*)d_in[1];
    const float* W_emb = (const float*)d_in[2];
    const float* b_emb = (const float*)d_in[3];
    const float* W1    = (const float*)d_in[4];
    const float* b1    = (const float*)d_in[5];
    const float* g1    = (const float*)d_in[6];
    const float* be1   = (const float*)d_in[7];
    const float* m1    = (const float*)d_in[8];
    const float* v1    = (const float*)d_in[9];
    const float* W2    = (const float*)d_in[10];
    const float* b2    = (const float*)d_in[11];
    const float* g2    = (const float*)d_in[12];
    const float* be2   = (const float*)d_in[13];
    const float* m2    = (const float*)d_in[14];
    const float* v2    = (const float*)d_in[15];
    const float* W_cls = (const float*)d_in[16];
    const float* b_cls = (const float*)d_in[17];
    float* out = (float*)d_out;

    const int* src = ei;          // edge_index[0]
    const int* dst = ei + NE;     // edge_index[1]

    const long NP = (NN + 511) & ~511;            // 100352
    float*  dinv    = (float*)d_ws;               // NP
    int*    cnt     = (int*)(dinv + NP);          // NP
    int*    row_ptr = cnt + NP;                   // NP (N+1 fits)
    int*    partials= row_ptr + NP;               // 1024
    int*    rank    = partials + 1024;            // NE
    int*    ent     = rank + NE;                  // NE
    float*  bufA    = (float*)(ent + NE);         // N*H f32
    __half* hwH     = (__half*)(bufA + (long)NN * HD);  // N*H fp16

    // zero cnt (memset node — capturable)
    hipMemsetAsync(cnt, 0, NN * sizeof(int), stream);

    // hist (rank-recording) || embed
    k_hist_embed<<<HIST_NB + EMB_NB, 256, 0, stream>>>(dst, cnt, rank, x, W_emb, b_emb, bufA);

    // dinv + scan1 || gemm layer 1 (f32 -> fp16 hw)
    k_scan1_gemm1<<<SCAN_NB + GEMM_NB, 256, 0, stream>>>(cnt, dinv, row_ptr, partials,
                                                         bufA, W1, hwH);
    k_scan2<<<1, 512, 0, stream>>>(partials);

    // fill (atomic-free, partials inline)
    k_fill<<<HIST_NB, 256, 0, stream>>>(src, dst, rank, row_ptr, partials, ent);

    // gather layer 1 -> bufA (f32)
    k_gather_bn_t<0><<<(NN + 3) / 4, 256, 0, stream>>>(hwH, dinv, row_ptr, partials, ent,
                                                       b1, g1, be1, m1, v1, bufA,
                                                       nullptr, nullptr);
    // gemm layer 2 (f32 -> fp16 hw)
    k_gemm<<<GEMM_NB, 256, 0, stream>>>(bufA, W2, hwH);

    // gather layer 2 + BN + ReLU + classifier -> out
    k_gather_bn_t<1><<<(NN + 3) / 4, 256, 0, stream>>>(hwH, dinv, row_ptr, partials, ent,
                                                       b2, g2, be2, m2, v2, out,
                                                       W_cls, b_cls);
}

// Round 13
// 236.262 us; speedup vs baseline: 5.2866x; 1.1571x over previous
//
#include <hip/hip_runtime.h>
#include <hip/hip_fp16.h>

#define NN 100000      // nodes
#define NE 1200000     // edges
#define FIN 22
#define HD 64
#define NC 6
#define BN_EPS 1e-5f
#define EPB 4096                          // edges per phase-1 block
#define MB1 ((NE + EPB - 1) / EPB)        // 293
#define NBK 196                           // coarse buckets of 512 nodes (dst>>9)
#define EMB_NB ((NN + 3) / 4)             // 25000
#define GEMM_NB ((NN + 63) / 64)          // 1563

// ---------------- fused: coarse-bucket histogram (LDS) || embed ----------------
__global__ void k_hist_embed(const int* __restrict__ dst, int* __restrict__ bktCnt,
                             const float* __restrict__ x, const float* __restrict__ W,
                             const float* __restrict__ b, float* __restrict__ h) {
    __shared__ float Ws[FIN * HD];
    __shared__ float xs[4][FIN];
    __shared__ int hist[256];
    int t = threadIdx.x;
    if (blockIdx.x < MB1) {
        hist[t] = 0;
        __syncthreads();
        int e0 = blockIdx.x * EPB;
        int e1 = min(e0 + EPB, NE);
        for (int e = e0 + t; e < e1; e += 256)
            atomicAdd(&hist[dst[e] >> 9], 1);          // LDS atomic
        __syncthreads();
        if (t < NBK && hist[t] > 0) atomicAdd(&bktCnt[t], hist[t]);  // 256/block global
        return;
    }
    int bid = blockIdx.x - MB1;
    for (int i = t; i < FIN * HD; i += 256) Ws[i] = W[i];
    int n0 = bid * 4;
    for (int i = t; i < 4 * FIN; i += 256) {
        int n = n0 + i / FIN;
        xs[i / FIN][i % FIN] = (n < NN) ? x[(long)n * FIN + i % FIN] : 0.f;
    }
    __syncthreads();
    int local = t >> 6;
    int f = t & 63;
    int n = n0 + local;
    if (n < NN) {
        float acc = b[f];
#pragma unroll
        for (int k = 0; k < FIN; ++k) acc = fmaf(xs[local][k], Ws[k * HD + f], acc);
        h[(long)n * HD + f] = fmaxf(acc, 0.f);
    }
}

// ---------------- bucket scan (1 block): bktBase = excl scan; cursor init ----------------
__global__ void k_bkt_scan(const int* __restrict__ bktCnt, int* __restrict__ bktBase,
                           int* __restrict__ cursor) {
    __shared__ int s[256];
    int t = threadIdx.x;
    int v = (t < NBK) ? bktCnt[t] : 0;
    s[t] = v;
    __syncthreads();
    for (int off = 1; off < 256; off <<= 1) {
        int x = (t >= off) ? s[t - off] : 0;
        __syncthreads();
        s[t] += x;
        __syncthreads();
    }
    int excl = s[t] - v;
    if (t < NBK) { bktBase[t] = excl; cursor[t] = excl; }
    if (t == NBK - 1) bktBase[NBK] = excl + v;          // = NE
}

// ---------------- bin scatter: edges -> bucket-contiguous (src,dst) pairs ----------------
__global__ void k_bin(const int* __restrict__ src, const int* __restrict__ dst,
                      int* __restrict__ cursor, int2* __restrict__ binned) {
    __shared__ int hist[256];
    __shared__ int sbase[256];
    __shared__ int lcur[256];
    int t = threadIdx.x;
    hist[t] = 0;
    __syncthreads();
    int e0 = blockIdx.x * EPB;
    int e1 = min(e0 + EPB, NE);
    for (int e = e0 + t; e < e1; e += 256)
        atomicAdd(&hist[dst[e] >> 9], 1);
    __syncthreads();
    if (hist[t] > 0) sbase[t] = atomicAdd(&cursor[t], hist[t]);  // claim range
    lcur[t] = 0;
    __syncthreads();
    for (int e = e0 + t; e < e1; e += 256) {
        int d = dst[e];
        int bk = d >> 9;
        int idx = atomicAdd(&lcur[bk], 1);              // LDS atomic
        binned[sbase[bk] + idx] = make_int2(src[e], d);
    }
}

// ---------------- gemm body: hw(fp16) = hin(f32) @ W ----------------
// 64 nodes per tile; h staged transposed in LDS; unroll capped at 8 (VGPR spill
// at full unroll caused 1.5 GB scratch traffic in round 3).
__device__ __forceinline__ void gemm_tile(int n0, int t,
                                          const float* __restrict__ hin,
                                          const float* __restrict__ W,
                                          __half* __restrict__ hw,
                                          float* Ws, float* hsT) {
    for (int i = t; i < 1024; i += 256)
        reinterpret_cast<float4*>(Ws)[i] = reinterpret_cast<const float4*>(W)[i];
    for (int i = t; i < 1024; i += 256) {
        int node = i & 63;
        int kq = i >> 6;
        int n = n0 + node;
        float4 val = (n < NN) ? *reinterpret_cast<const float4*>(&hin[(long)n * HD + kq * 4])
                              : make_float4(0.f, 0.f, 0.f, 0.f);
        hsT[(kq * 4 + 0) * 64 + node] = val.x;
        hsT[(kq * 4 + 1) * 64 + node] = val.y;
        hsT[(kq * 4 + 2) * 64 + node] = val.z;
        hsT[(kq * 4 + 3) * 64 + node] = val.w;
    }
    __syncthreads();
    int fq = t & 15;
    int ng = t >> 4;
    float4 a0 = {0,0,0,0}, a1 = {0,0,0,0}, a2 = {0,0,0,0}, a3 = {0,0,0,0};
#pragma unroll 8
    for (int k = 0; k < HD; ++k) {
        float4 w = *reinterpret_cast<const float4*>(&Ws[k * HD + fq * 4]);
        float4 h4 = *reinterpret_cast<const float4*>(&hsT[k * 64 + ng * 4]);
        a0.x = fmaf(h4.x, w.x, a0.x); a0.y = fmaf(h4.x, w.y, a0.y);
        a0.z = fmaf(h4.x, w.z, a0.z); a0.w = fmaf(h4.x, w.w, a0.w);
        a1.x = fmaf(h4.y, w.x, a1.x); a1.y = fmaf(h4.y, w.y, a1.y);
        a1.z = fmaf(h4.y, w.z, a1.z); a1.w = fmaf(h4.y, w.w, a1.w);
        a2.x = fmaf(h4.z, w.x, a2.x); a2.y = fmaf(h4.z, w.y, a2.y);
        a2.z = fmaf(h4.z, w.z, a2.z); a2.w = fmaf(h4.z, w.w, a2.w);
        a3.x = fmaf(h4.w, w.x, a3.x); a3.y = fmaf(h4.w, w.y, a3.y);
        a3.z = fmaf(h4.w, w.z, a3.z); a3.w = fmaf(h4.w, w.w, a3.w);
    }
    int nb = n0 + ng * 4;
    float4 accs[4] = {a0, a1, a2, a3};
#pragma unroll
    for (int q = 0; q < 4; ++q) {
        if (nb + q < NN) {
            __half2 lo = __floats2half2_rn(accs[q].x, accs[q].y);
            __half2 hi = __floats2half2_rn(accs[q].z, accs[q].w);
            int2 pk;
            pk.x = *reinterpret_cast<int*>(&lo);
            pk.y = *reinterpret_cast<int*>(&hi);
            *reinterpret_cast<int2*>(&hw[(long)(nb + q) * HD + fq * 4]) = pk;
        }
    }
}

// ---------------- fused: per-bucket CSR build (LDS hist+scan) || gemm layer 1 ----------------
__global__ void k_build_gemm1(const int2* __restrict__ binned, const int* __restrict__ bktBase,
                              int* __restrict__ row_ptr, float* __restrict__ dinv,
                              int* __restrict__ ent,
                              const float* __restrict__ hin, const float* __restrict__ W,
                              __half* __restrict__ hw) {
    __shared__ float Ws[HD * HD];       // gemm path
    __shared__ float hsT[HD * 64];
    __shared__ int cnt[512];            // build path
    __shared__ int excl[512];
    __shared__ int s1[256];
    __shared__ int cur[512];
    int t = threadIdx.x;
    if (blockIdx.x < NBK) {
        int bk = blockIdx.x;
        int base = bktBase[bk], end = bktBase[bk + 1];
        cnt[t] = 0; cnt[t + 256] = 0;
        __syncthreads();
        for (int i = base + t; i < end; i += 256)
            atomicAdd(&cnt[binned[i].y & 511], 1);      // LDS atomic
        __syncthreads();
        s1[t] = cnt[2 * t] + cnt[2 * t + 1];
        __syncthreads();
        int v = s1[t];
        for (int off = 1; off < 256; off <<= 1) {
            int x = (t >= off) ? s1[t - off] : 0;
            __syncthreads();
            s1[t] += x;
            __syncthreads();
        }
        int ep = s1[t] - v;                              // exclusive over pairs
        excl[2 * t] = ep;
        excl[2 * t + 1] = ep + cnt[2 * t];
        __syncthreads();
#pragma unroll
        for (int q = 0; q < 2; ++q) {
            int ln = 2 * t + q;
            int node = bk * 512 + ln;                    // < 196*512 = 100352 = NP
            row_ptr[node] = base + excl[ln];             // row_ptr[NN] lands = NE
            dinv[node] = rsqrtf((float)cnt[ln] + 1.0f);  // +1 self loop
        }
        cur[2 * t] = excl[2 * t];
        cur[2 * t + 1] = excl[2 * t + 1];
        __syncthreads();
        for (int i = base + t; i < end; i += 256) {
            int2 ed = binned[i];
            int ln = ed.y & 511;
            int pos = base + atomicAdd(&cur[ln], 1);     // LDS atomic
            ent[pos] = ed.x;
        }
        return;
    }
    gemm_tile((blockIdx.x - NBK) * 64, t, hin, W, hw, Ws, hsT);
}

// ---------------- layer-2 gemm ----------------
__global__ void k_gemm(const float* __restrict__ hin, const float* __restrict__ W,
                       __half* __restrict__ hw) {
    __shared__ float Ws[HD * HD];
    __shared__ float hsT[HD * 64];
    gemm_tile(blockIdx.x * 64, threadIdx.x, hin, W, hw, Ws, hsT);
}

// ---------------- gather + self-loop + bias + BN + ReLU (+ optional classifier) ----------------
// one wave per node; 4 groups x 16 lanes; hw is fp16 (8B/lane row reads).
template <int WITH_CLS>
__global__ void k_gather_bn_t(const __half* __restrict__ hw, const float* __restrict__ dinv,
                              const int* __restrict__ row_ptr, const int* __restrict__ ent,
                              const float* __restrict__ bias, const float* __restrict__ g,
                              const float* __restrict__ be, const float* __restrict__ m,
                              const float* __restrict__ v, float* __restrict__ out,
                              const float* __restrict__ Wc, const float* __restrict__ bc) {
    int t = threadIdx.x;
    int n = blockIdx.x * 4 + (t >> 6);
    if (n >= NN) return;
    int l = t & 63;
    int grp = l >> 4;
    int j = l & 15;
    float di = dinv[n];
    float4 acc = {0.f, 0.f, 0.f, 0.f};
    int b0 = row_ptr[n], b1 = row_ptr[n + 1];
    int e = b0 + grp;
    int s = 0; float dv = 0.f;
    if (e < b1) { s = ent[e]; dv = dinv[s]; }
    while (e < b1) {
        int e2 = e + 4;
        int sn = 0; float dvn = 0.f;
        if (e2 < b1) { sn = ent[e2]; dvn = dinv[sn]; }   // prefetch next
        float c = dv * di;
        int2 rv = *reinterpret_cast<const int2*>(&hw[(long)s * HD + j * 4]);
        float2 f0 = __half22float2(*reinterpret_cast<__half2*>(&rv.x));
        float2 f1 = __half22float2(*reinterpret_cast<__half2*>(&rv.y));
        acc.x = fmaf(f0.x, c, acc.x);
        acc.y = fmaf(f0.y, c, acc.y);
        acc.z = fmaf(f1.x, c, acc.z);
        acc.w = fmaf(f1.y, c, acc.w);
        s = sn; dv = dvn; e = e2;
    }
#pragma unroll
    for (int off = 16; off < 64; off <<= 1) {
        acc.x += __shfl_xor(acc.x, off, 64);
        acc.y += __shfl_xor(acc.y, off, 64);
        acc.z += __shfl_xor(acc.z, off, 64);
        acc.w += __shfl_xor(acc.w, off, 64);
    }
    if (grp == 0) {
        float dd = di * di;
        int2 sv = *reinterpret_cast<const int2*>(&hw[(long)n * HD + j * 4]);
        float2 s0 = __half22float2(*reinterpret_cast<__half2*>(&sv.x));
        float2 s1 = __half22float2(*reinterpret_cast<__half2*>(&sv.y));
        acc.x = fmaf(s0.x, dd, acc.x);
        acc.y = fmaf(s0.y, dd, acc.y);
        acc.z = fmaf(s1.x, dd, acc.z);
        acc.w = fmaf(s1.y, dd, acc.w);
        int f = j * 4;
        float4 gv = *reinterpret_cast<const float4*>(&g[f]);
        float4 vv = *reinterpret_cast<const float4*>(&v[f]);
        float4 bv = *reinterpret_cast<const float4*>(&bias[f]);
        float4 mv = *reinterpret_cast<const float4*>(&m[f]);
        float4 bev = *reinterpret_cast<const float4*>(&be[f]);
        float4 o;
        o.x = fmaxf((acc.x + bv.x - mv.x) * (gv.x * rsqrtf(vv.x + BN_EPS)) + bev.x, 0.f);
        o.y = fmaxf((acc.y + bv.y - mv.y) * (gv.y * rsqrtf(vv.y + BN_EPS)) + bev.y, 0.f);
        o.z = fmaxf((acc.z + bv.z - mv.z) * (gv.z * rsqrtf(vv.z + BN_EPS)) + bev.z, 0.f);
        o.w = fmaxf((acc.w + bv.w - mv.w) * (gv.w * rsqrtf(vv.w + BN_EPS)) + bev.w, 0.f);
        if (WITH_CLS == 0) {
            *reinterpret_cast<float4*>(&out[(long)n * HD + j * 4]) = o;
        } else {
            float accC[NC];
#pragma unroll
            for (int c = 0; c < NC; ++c) {
                accC[c] = o.x * Wc[(4 * j + 0) * NC + c]
                        + o.y * Wc[(4 * j + 1) * NC + c]
                        + o.z * Wc[(4 * j + 2) * NC + c]
                        + o.w * Wc[(4 * j + 3) * NC + c];
            }
#pragma unroll
            for (int off = 1; off < 16; off <<= 1) {
#pragma unroll
                for (int c = 0; c < NC; ++c) accC[c] += __shfl_xor(accC[c], off, 64);
            }
            if (j == 0) {
#pragma unroll
                for (int c = 0; c < NC; ++c) out[(long)n * NC + c] = accC[c] + bc[c];
            }
        }
    }
}

extern "C" void kernel_launch(void* const* d_in, const int* in_sizes, int n_in,
                              void* d_out, int out_size, void* d_ws, size_t ws_size,
                              hipStream_t stream) {
    const float* x     = (const float*)d_in[0];
    const int*   ei    = (const int*)d_in[1];
    const float* W_emb = (const float*)d_in[2];
    const float* b_emb = (const float*)d_in[3];
    const float* W1    = (const float*)d_in[4];
    const float* b1    = (const float*)d_in[5];
    const float* g1    = (const float*)d_in[6];
    const float* be1   = (const float*)d_in[7];
    const float* m1    = (const float*)d_in[8];
    const float* v1    = (const float*)d_in[9];
    const float* W2    = (const float*)d_in[10];
    const float* b2    = (const float*)d_in[11];
    const float* g2    = (const float*)d_in[12];
    const float* be2   = (const float*)d_in[13];
    const float* m2    = (const float*)d_in[14];
    const float* v2    = (const float*)d_in[15];
    const float* W_cls = (const float*)d_in[16];
    const float* b_cls = (const float*)d_in[17];
    float* out = (float*)d_out;

    const int* src = ei;          // edge_index[0]
    const int* dst = ei + NE;     // edge_index[1]

    const long NP = 100352;                       // 196*512, >= NN+1
    float* dinv    = (float*)d_ws;                // NP
    int*   row_ptr = (int*)(dinv + NP);           // NP
    int*   bktCnt  = row_ptr + NP;                // 256
    int*   bktBase = bktCnt + 256;                // 512 (need 197)
    int*   cursor  = bktBase + 512;               // 256
    int2*  binned  = (int2*)(cursor + 256);       // NE * 8B (8B-aligned)
    int*   ent     = (int*)(binned + NE);         // NE
    float* bufA    = (float*)(ent + NE);          // N*H f32
    __half* hwH    = (__half*)(bufA + (long)NN * HD);  // N*H fp16

    // zero bucket counters (1 KB)
    hipMemsetAsync(bktCnt, 0, 256 * sizeof(int), stream);

    // coarse LDS histogram || embed
    k_hist_embed<<<MB1 + EMB_NB, 256, 0, stream>>>(dst, bktCnt, x, W_emb, b_emb, bufA);

    // bucket scan + cursor init
    k_bkt_scan<<<1, 256, 0, stream>>>(bktCnt, bktBase, cursor);

    // bin edges into bucket-contiguous regions
    k_bin<<<MB1, 256, 0, stream>>>(src, dst, cursor, binned);

    // per-bucket CSR build (row_ptr, dinv, ent) || gemm layer 1 (f32 -> fp16)
    k_build_gemm1<<<NBK + GEMM_NB, 256, 0, stream>>>(binned, bktBase, row_ptr, dinv, ent,
                                                     bufA, W1, hwH);

    // gather layer 1 -> bufA (f32)
    k_gather_bn_t<0><<<EMB_NB, 256, 0, stream>>>(hwH, dinv, row_ptr, ent,
                                                 b1, g1, be1, m1, v1, bufA,
                                                 nullptr, nullptr);
    // gemm layer 2 (f32 -> fp16)
    k_gemm<<<GEMM_NB, 256, 0, stream>>>(bufA, W2, hwH);

    // gather layer 2 + BN + ReLU + classifier -> out
    k_gather_bn_t<1><<<EMB_NB, 256, 0, stream>>>(hwH, dinv, row_ptr, ent,
                                                 b2, g2, be2, m2, v2, out,
                                                 W_cls, b_cls);
}